// Round 3
// baseline (9919.079 us; speedup 1.0000x reference)
//
#include <hip/hip_runtime.h>
#include <math.h>

#define NNEUR 300          // NN
#define NFEAT 20           // NF
#define NPAD  320          // padded n-dimension
#define MAUGP 336          // 300 r + 20 image + 1 hold + 1 const + 14 pad = 16*21
#define NOUT  50
#define NPMAC 100          // NPM
#define TSTEPS 500
#define BATCH 1024
#define NWAVE 16
#define MCHUNK 21          // m-rows per wave
#define RROWS 17           // rows held in registers (17*5 = 85 VGPRs)
#define LROWS 4            // rows held in LDS

// Augmented transposed weight matrix W[m][n], n padded to 320:
//   m in [0,300):   W[m][n] = J[n][m]
//   m in [300,320): W[m][n] = I[n][m-300]
//   m == 320:       W[m][n] = S[n]
//   m == 321:       W[m][n] = Bb[n]   (activation fixed at 1)
//   else / n>=300:  0
__global__ void build_w_kernel(const float* __restrict__ J,
                               const float* __restrict__ I,
                               const float* __restrict__ S,
                               const float* __restrict__ Bb,
                               float* __restrict__ W) {
    int e = blockIdx.x * 256 + threadIdx.x;
    if (e >= MAUGP * NPAD) return;
    int m = e / NPAD, n = e % NPAD;
    float v = 0.0f;
    if (n < NNEUR) {
        if (m < NNEUR)                   v = J[n * NNEUR + m];
        else if (m < NNEUR + NFEAT)      v = I[n * NFEAT + (m - NNEUR)];
        else if (m == NNEUR + NFEAT)     v = S[n];
        else if (m == NNEUR + NFEAT + 1) v = Bb[n];
    }
    W[e] = v;
}

// Persistent RNN: 256 blocks x 1024 threads (16 waves), 1 block/CU.
// Lane l owns n in {4l,4l+1,4l+2,4l+3} U {256+l}.
// Wave owns m-rows [21*wid, 21*wid+21): 17 rows pinned in VGPRs, 4 in LDS.
__global__ __launch_bounds__(1024, 4) void rnn_kernel(
    const float* __restrict__ W,      // [MAUGP][NPAD]
    const float* __restrict__ data,   // [T][21][B]
    const float* __restrict__ x0,     // [NNEUR]
    const float* __restrict__ fcw,    // [NOUT][NPMAC]
    const float* __restrict__ fcb,    // [NOUT]
    float* __restrict__ out)          // [T][B][NOUT]
{
    __shared__ __align__(16) float Wl[NWAVE][LROWS][NPAD];   // 80 KB
    __shared__ __align__(16) float part[8][4][NPAD];         // 40 KB
    __shared__ __align__(16) float raug[MAUGP][4];           // 5.4 KB
    __shared__ __align__(16) float xs[4][NPAD];              // 5 KB
    __shared__ float fcwt[NPMAC][NOUT];                      // 20 KB
    __shared__ float fcbs[NOUT];

    const int tid = threadIdx.x;
    const int wid = tid >> 6;
    const int l   = tid & 63;
    const int b0  = blockIdx.x * 4;
    const int m0  = wid * MCHUNK;

    // ---- init: zero raug, load fc weights ----
    for (int i = tid; i < MAUGP * 4; i += 1024) ((float*)raug)[i] = 0.0f;
    for (int i = tid; i < NPMAC * NOUT; i += 1024) {
        int p = i / NOUT, o = i - p * NOUT;
        fcwt[p][o] = fcw[o * NPMAC + p];
    }
    if (tid < NOUT) fcbs[tid] = fcb[tid];
    __syncthreads();

    for (int i = tid; i < NNEUR; i += 1024) {
        float xv = x0[i];
        float rv = fmaxf(tanhf(xv), 0.0f);
        #pragma unroll
        for (int b = 0; b < 4; ++b) { xs[b][i] = xv; raug[i][b] = rv; }
    }
    if (tid < 4) raug[NNEUR + NFEAT + 1][tid] = 1.0f;   // const row

    // ---- load weight chunk: 17 rows -> pinned VGPRs, 4 rows -> LDS ----
    float4 w4[RROWS];
    float  wt[RROWS];
    #pragma unroll
    for (int i = 0; i < RROWS; ++i) {
        w4[i] = *reinterpret_cast<const float4*>(&W[(size_t)(m0 + i) * NPAD + 4 * l]);
        wt[i] = W[(size_t)(m0 + i) * NPAD + 256 + l];
    }
    // Pin: opaque def prevents the compiler from rematerializing the global
    // loads inside the t-loop (round-2 showed VGPR_Count=64 => it re-streamed
    // W from L2 every step).
    #pragma unroll
    for (int i = 0; i < RROWS; ++i) {
        asm volatile("" : "+v"(w4[i].x), "+v"(w4[i].y), "+v"(w4[i].z), "+v"(w4[i].w));
        asm volatile("" : "+v"(wt[i]));
    }
    #pragma unroll
    for (int i = 0; i < LROWS; ++i) {
        *reinterpret_cast<float4*>(&Wl[wid][i][4 * l]) =
            *reinterpret_cast<const float4*>(&W[(size_t)(m0 + RROWS + i) * NPAD + 4 * l]);
        Wl[wid][i][256 + l] = W[(size_t)(m0 + RROWS + i) * NPAD + 256 + l];
    }

    // prefetch data[t=0] slice (21 rows x 4 batch)
    float4 dstage = make_float4(0.f, 0.f, 0.f, 0.f);
    if (tid < NFEAT + 1)
        dstage = *reinterpret_cast<const float4*>(data + (size_t)tid * BATCH + b0);
    __syncthreads();

    for (int t = 0; t < TSTEPS; ++t) {
        // ---- Phase A: commit data[t], prefetch data[t+1] ----
        if (tid < NFEAT + 1) {
            *reinterpret_cast<float4*>(&raug[NNEUR + tid][0]) = dstage;
            if (t + 1 < TSTEPS)
                dstage = *reinterpret_cast<const float4*>(
                    data + ((size_t)(t + 1) * (NFEAT + 1) + tid) * BATCH + b0);
        }
        __syncthreads();

        // ---- Phase B: per-wave matvec over its 21-row m-chunk ----
        float acc[4][4];    // acc[j][b], n = 4l+j
        float acct[4];      // n = 256+l
        #pragma unroll
        for (int j = 0; j < 4; ++j)
            #pragma unroll
            for (int b = 0; b < 4; ++b) acc[j][b] = 0.0f;
        #pragma unroll
        for (int b = 0; b < 4; ++b) acct[b] = 0.0f;

        #pragma unroll
        for (int i = 0; i < RROWS; ++i) {
            const float4 rv = *reinterpret_cast<const float4*>(&raug[m0 + i][0]);
            const float rb[4] = {rv.x, rv.y, rv.z, rv.w};
            const float wj[4] = {w4[i].x, w4[i].y, w4[i].z, w4[i].w};
            #pragma unroll
            for (int j = 0; j < 4; ++j)
                #pragma unroll
                for (int b = 0; b < 4; ++b)
                    acc[j][b] += wj[j] * rb[b];
            #pragma unroll
            for (int b = 0; b < 4; ++b) acct[b] += wt[i] * rb[b];
        }
        #pragma unroll
        for (int i = 0; i < LROWS; ++i) {
            const float4 rv = *reinterpret_cast<const float4*>(&raug[m0 + RROWS + i][0]);
            const float rb[4] = {rv.x, rv.y, rv.z, rv.w};
            const float4 wv = *reinterpret_cast<const float4*>(&Wl[wid][i][4 * l]);
            const float wlt = Wl[wid][i][256 + l];
            const float wj[4] = {wv.x, wv.y, wv.z, wv.w};
            #pragma unroll
            for (int j = 0; j < 4; ++j)
                #pragma unroll
                for (int b = 0; b < 4; ++b)
                    acc[j][b] += wj[j] * rb[b];
            #pragma unroll
            for (int b = 0; b < 4; ++b) acct[b] += wlt * rb[b];
        }

        // ---- two-stage partial reduce: waves 0-7 write, 8-15 RMW-add ----
        if (wid < 8) {
            #pragma unroll
            for (int b = 0; b < 4; ++b) {
                float4 v = make_float4(acc[0][b], acc[1][b], acc[2][b], acc[3][b]);
                *reinterpret_cast<float4*>(&part[wid][b][4 * l]) = v;
                part[wid][b][256 + l] = acct[b];
            }
        }
        __syncthreads();
        if (wid >= 8) {
            #pragma unroll
            for (int b = 0; b < 4; ++b) {
                float4 p4 = *reinterpret_cast<float4*>(&part[wid - 8][b][4 * l]);
                p4.x += acc[0][b]; p4.y += acc[1][b];
                p4.z += acc[2][b]; p4.w += acc[3][b];
                *reinterpret_cast<float4*>(&part[wid - 8][b][4 * l]) = p4;
                part[wid - 8][b][256 + l] += acct[b];
            }
        }
        __syncthreads();

        // ---- Phase C: reduce 8 partials, state update, write r ----
        {
            int b = tid / NPAD;
            int n = tid - b * NPAD;
            if (n < NNEUR) {
                float s = 0.0f;
                #pragma unroll
                for (int w8 = 0; w8 < 8; ++w8) s += part[w8][b][n];
                float xo  = xs[b][n];
                float pre = xo + (s - xo) * 0.1f;     // x + tdx/10
                xs[b][n] = pre;
                raug[n][b] = fmaxf(tanhf(pre), 0.0f);
            }
            if (tid < 256) {                           // items 1024..1279 -> b=3
                int n2 = 64 + tid;
                if (n2 < NNEUR) {
                    float s = 0.0f;
                    #pragma unroll
                    for (int w8 = 0; w8 < 8; ++w8) s += part[w8][3][n2];
                    float xo  = xs[3][n2];
                    float pre = xo + (s - xo) * 0.1f;
                    xs[3][n2] = pre;
                    raug[n2][3] = fmaxf(tanhf(pre), 0.0f);
                }
            }
        }
        __syncthreads();

        // ---- Phase D: y = r[:, :100] @ fcw.T + fcb, 4 threads per (b,o) ----
        if (tid < 800) {
            int pair = tid >> 2, seg = tid & 3;
            int b = pair / NOUT, o = pair - (pair / NOUT) * NOUT;
            int pb = seg * 25;
            float y = 0.0f;
            #pragma unroll 5
            for (int k = 0; k < 25; ++k)
                y += raug[pb + k][b] * fcwt[pb + k][o];
            y += __shfl_down(y, 1, 4);
            y += __shfl_down(y, 2, 4);
            if (seg == 0)
                out[((size_t)t * BATCH + b0 + b) * NOUT + o] = y + fcbs[o];
        }
        // no barrier: D reads raug rows <100; next A writes rows >=300; the
        // A-end barrier orders everything before the next part-write.
    }
}

extern "C" void kernel_launch(void* const* d_in, const int* in_sizes, int n_in,
                              void* d_out, int out_size, void* d_ws, size_t ws_size,
                              hipStream_t stream) {
    const float* data = (const float*)d_in[0];
    const float* J    = (const float*)d_in[1];
    const float* I    = (const float*)d_in[2];
    const float* S    = (const float*)d_in[3];
    const float* Bb   = (const float*)d_in[4];
    const float* x0   = (const float*)d_in[5];
    const float* fcw  = (const float*)d_in[6];
    const float* fcb  = (const float*)d_in[7];
    float* out = (float*)d_out;
    float* W   = (float*)d_ws;   // MAUGP*NPAD*4 = 430,080 bytes

    int wtot = MAUGP * NPAD;
    build_w_kernel<<<(wtot + 255) / 256, 256, 0, stream>>>(J, I, S, Bb, W);
    rnn_kernel<<<256, 1024, 0, stream>>>(W, data, x0, fcw, fcb, out);
}